// Round 9
// baseline (134006.970 us; speedup 1.0000x reference)
//
#include <hip/hip_runtime.h>
#include <stdint.h>
#include <math.h>

// Problem constants
#define Bv      512
#define INv     64
#define Hv      512
#define OUTv    12
#define Tv      31
#define S0v     8
#define STEPS   (Tv*Bv)        // 15872 sequential LSTM steps per layer

// Workgroup roles — 1024-thread blocks (16 waves); 24 LSTM sync domains
#define KA      8              // layer-0 WGs (64 h each, 4 h per wave)
#define KB      16             // layer-1 WGs (32 h each, 2 h per wave)
#define KPP     16             // postproc WGs
#define NBLK    (KA+KB+KPP)    // 40 blocks
#define RING    32             // comm ring depth (power of 2)

// ws layout (bytes), total 32,903,168 (same as r6/r8):
//  [0, 64)        : iterflag u32[16]
//  [4096,   +128K): h0A u64[RING][512]  — read by L0
//  [135168, +128K): h0B u64[RING][512]  — read by L1
//  [266240, +128K): y1c u64[RING][512]  — read by L1 (+ L0 throttle, sparse)
//  [397312, ...)  : ys1 float[STEPS][512]  (plain, fenced per iteration)

// ---------------- threefry2x32 (JAX-exact) ----------------
__device__ __forceinline__ uint32_t rotl32(uint32_t v, int r){ return (v<<r)|(v>>(32-r)); }

__device__ __forceinline__ void threefry2x32(uint32_t k0, uint32_t k1,
                                             uint32_t x0, uint32_t x1,
                                             uint32_t& o0, uint32_t& o1) {
  uint32_t ks2 = k0 ^ k1 ^ 0x1BD11BDAu;
  x0 += k0; x1 += k1;
#define TFR(r) { x0 += x1; x1 = rotl32(x1, r); x1 ^= x0; }
  TFR(13) TFR(15) TFR(26) TFR(6)
  x0 += k1;  x1 += ks2 + 1u;
  TFR(17) TFR(29) TFR(16) TFR(24)
  x0 += ks2; x1 += k0 + 2u;
  TFR(13) TFR(15) TFR(26) TFR(6)
  x0 += k0;  x1 += k1 + 3u;
  TFR(17) TFR(29) TFR(16) TFR(24)
  x0 += k1;  x1 += ks2 + 4u;
  TFR(13) TFR(15) TFR(26) TFR(6)
  x0 += ks2; x1 += k0 + 5u;
#undef TFR
  o0 = x0; o1 = x1;
}

__device__ __forceinline__ uint32_t tf_bits32(uint32_t k0, uint32_t k1, uint32_t j) {
  uint32_t a, b;
  threefry2x32(k0, k1, 0u, j, a, b);
  return a ^ b;
}

__device__ __forceinline__ float u32_to_uniform(uint32_t bits) {
  float f = __uint_as_float(0x3F800000u | (bits >> 9)) - 1.0f;
  const float TINY = 1.17549435e-38f;
  return fmaxf(TINY, f + TINY);
}

__device__ __forceinline__ float gumbelf(uint32_t bits) {
  float u = u32_to_uniform(bits);
  return -logf(-logf(u));
}

__device__ __forceinline__ float sigmf(float x) {
  if (x >= 0.f) { float z = expf(-x); return 1.f/(1.f+z); }
  float z = expf(x); return z/(1.f+z);
}

// Butterfly: halve per-lane row-partials across lanes (xor mask m).
template<int N>
__device__ __forceinline__ void bfly_halve(float* v, int m) {
  int lane = threadIdx.x & 63;
  bool up = (lane & m) != 0;
#pragma unroll
  for (int j = 0; j < N/2; ++j) {
    float send = up ? v[j] : v[j + N/2];
    float recv = __shfl_xor(send, m, 64);
    v[j] = (up ? v[j + N/2] : v[j]) + recv;
  }
}

__device__ __forceinline__ uint64_t aload64(const uint64_t* p){
  return __hip_atomic_load(p, __ATOMIC_RELAXED, __HIP_MEMORY_SCOPE_AGENT);
}
__device__ __forceinline__ void astore64(uint64_t* p, uint64_t v){
  __hip_atomic_store(p, v, __ATOMIC_RELAXED, __HIP_MEMORY_SCOPE_AGENT);
}
__device__ __forceinline__ uint32_t aload32(const uint32_t* p){
  return __hip_atomic_load(p, __ATOMIC_RELAXED, __HIP_MEMORY_SCOPE_AGENT);
}
__device__ __forceinline__ void astore32(uint32_t* p, uint32_t v){
  __hip_atomic_store(p, v, __ATOMIC_RELAXED, __HIP_MEMORY_SCOPE_AGENT);
}
__device__ __forceinline__ uint32_t tagof(uint64_t w){ return (uint32_t)(w>>32); }
__device__ __forceinline__ float    valof(uint64_t w){ return __uint_as_float((uint32_t)w); }
__device__ __forceinline__ uint64_t mkword(uint32_t t, float v){
  return ((uint64_t)t<<32) | (uint64_t)__float_as_uint(v);
}

__global__ __launch_bounds__(1024, 1)
void net_persistent(const float* __restrict__ Wih0, const float* __restrict__ Whh0,
                    const float* __restrict__ b0,
                    const float* __restrict__ Wih1, const float* __restrict__ Whh1,
                    const float* __restrict__ b1,
                    const float* __restrict__ gamma, const float* __restrict__ beta,
                    const float* __restrict__ Wout, const float* __restrict__ bout,
                    const float* __restrict__ h0in, const float* __restrict__ c0in,
                    float* __restrict__ out, uint32_t* __restrict__ wsu)
{
  uint32_t* iterflag = wsu;                              // [16]
  uint64_t* h0A = (uint64_t*)((char*)wsu + 4096);
  uint64_t* h0B = (uint64_t*)((char*)wsu + 4096 + (size_t)RING*Hv*8);
  uint64_t* y1c = (uint64_t*)((char*)wsu + 4096 + (size_t)2*RING*Hv*8);
  float*    ys1 = (float*)((char*)wsu + 4096 + (size_t)3*RING*Hv*8);

  const int bid  = blockIdx.x;
  const int tid  = threadIdx.x;
  const int wave = tid >> 6;
  const int lane = tid & 63;

  __shared__ float hbuf[2][Hv];      // L0 input double-buffer
  __shared__ float xbuf[2][2*Hv];    // L1 input double-buffer [x | hprev]
  __shared__ float Wout_s[OUTv*Hv];
  __shared__ float mu_s[Hv], isd_s[Hv], gam_s[Hv], bet_s[Hv];

  if (bid < KA) {
    // ================= Layer 0 (autonomous: x = ones folded) =================
    // 8 WGs x 1024 threads; wave (0..15) owns 4 h-indices.
    const int hbase = bid*64;
    float w[128];
#pragma unroll
    for (int jl = 0; jl < 4; ++jl)
#pragma unroll
      for (int g = 0; g < 4; ++g) {
        int r = jl*4 + g;
        const float* rp = Whh0 + (size_t)(g*Hv + hbase + wave*4 + jl)*Hv;
#pragma unroll
        for (int k = 0; k < 2; ++k) {
          float4 q = *(const float4*)(rp + k*256 + lane*4);
          w[r*8+k*4+0]=q.x; w[r*8+k*4+1]=q.y; w[r*8+k*4+2]=q.z; w[r*8+k*4+3]=q.w;
        }
      }
    // per-lane gate constants (x = ones folded) + c-state for h-index lane&3
    const int jsel = lane & 3;
    const int hg = hbase + wave*4 + jsel;
    float cgi, cgf, cgg, cgo;
    {
      float s0=b0[0*Hv+hg], s1=b0[1*Hv+hg], s2=b0[2*Hv+hg], s3=b0[3*Hv+hg];
      for (int k = 0; k < INv; ++k) {
        s0 += Wih0[(size_t)(0*Hv+hg)*INv+k];
        s1 += Wih0[(size_t)(1*Hv+hg)*INv+k];
        s2 += Wih0[(size_t)(2*Hv+hg)*INv+k];
        s3 += Wih0[(size_t)(3*Hv+hg)*INv+k];
      }
      cgi=s0; cgf=s1; cgg=s2; cgo=s3;
    }
    float cst = c0in[hg];

    for (int s = 0; s < STEPS; ++s) {
      const int par = s & 1;
      // ring throttle every 16 steps (same as r8): require L1 consumed
      // h0 tag >= s-16 before overwriting slots s-32..s-17.
      if ((s & 15) == 0 && s >= 32) {
        const uint64_t* tp = y1c + (size_t)((s-17)&(RING-1))*Hv + lane*8;
        uint32_t need = (uint32_t)(s - 16);
        for (;;) {
          uint32_t t = tagof(aload64(tp));
          if (__all((int)(t >= need && t <= (uint32_t)STEPS))) break;
          __builtin_amdgcn_s_sleep(1);
        }
      }
      // phase A: poll previous h into LDS — threads 0..511, 1 word each
      if (tid < Hv) {
        if (s == 0) {
          hbuf[0][tid] = h0in[tid];
        } else {
          const uint64_t* src = h0A + (size_t)((s-1)&(RING-1))*Hv + tid;
          uint32_t want = (uint32_t)s;
          uint64_t a = aload64(src);
          while (tagof(a) != want) a = aload64(src);
          hbuf[par][tid] = valof(a);
        }
      }
      __syncthreads();
      // compute: 16 rows x 8 cols per lane
      const float4* hv = (const float4*)(hbuf[par]);
      float4 vA = hv[lane], vB = hv[64 + lane];
      float acc[16];
#pragma unroll
      for (int r = 0; r < 16; ++r) {
        float a = 0.f;
        a = fmaf(w[r*8+0], vA.x, a); a = fmaf(w[r*8+1], vA.y, a);
        a = fmaf(w[r*8+2], vA.z, a); a = fmaf(w[r*8+3], vA.w, a);
        a = fmaf(w[r*8+4], vB.x, a); a = fmaf(w[r*8+5], vB.y, a);
        a = fmaf(w[r*8+6], vB.z, a); a = fmaf(w[r*8+7], vB.w, a);
        acc[r] = a;
      }
      bfly_halve<16>(acc, 32);
      bfly_halve<8>(acc, 16);
      bfly_halve<4>(acc, 8);
      bfly_halve<2>(acc, 4);
      acc[0] += __shfl_xor(acc[0], 2, 64);
      acc[0] += __shfl_xor(acc[0], 1, 64);   // lane holds row (lane>>2)
      // every lane gathers the 4 gates of h-index jsel
      float gi = __shfl(acc[0], 16*jsel + 0,  64);
      float gf = __shfl(acc[0], 16*jsel + 4,  64);
      float gg = __shfl(acc[0], 16*jsel + 8,  64);
      float go = __shfl(acc[0], 16*jsel + 12, 64);
      float cc = sigmf(gf+cgf)*cst + sigmf(gi+cgi)*tanhf(gg+cgg);
      float hh = sigmf(go+cgo)*tanhf(cc);
      cst = cc;
      if (lane < 8) {   // lanes 0-3 -> replica A (L0 readers); 4-7 -> B (L1 readers)
        uint64_t* dst = (lane < 4) ? h0A : h0B;
        astore64(dst + (size_t)(s&(RING-1))*Hv + hg, mkword((uint32_t)(s+1), hh));
      }
    }
  } else if (bid < KA + KB) {
    // ================= Layer 1 =================
    // 16 WGs x 1024 threads; wave (0..15) owns 2 h-indices.
    const int wg1 = bid - KA;
    const int hbase = wg1*32;
    float w[128];
#pragma unroll
    for (int jl = 0; jl < 2; ++jl)
#pragma unroll
      for (int g = 0; g < 4; ++g) {
        int r = jl*4 + g;
        int row = g*Hv + hbase + wave*2 + jl;
#pragma unroll
        for (int k = 0; k < 4; ++k) {
          int col = k*256 + lane*4;
          const float* M = (col < Hv) ? (Wih1 + (size_t)row*Hv + col)
                                      : (Whh1 + (size_t)row*Hv + (col - Hv));
          float4 q = *(const float4*)M;
          w[r*16+k*4+0]=q.x; w[r*16+k*4+1]=q.y; w[r*16+k*4+2]=q.z; w[r*16+k*4+3]=q.w;
        }
      }
    const int jsel = lane & 1;
    const int hg = hbase + wave*2 + jsel;
    float cgi = b1[0*Hv+hg], cgf = b1[1*Hv+hg],
          cgg = b1[2*Hv+hg], cgo = b1[3*Hv+hg];
    float cst = c0in[Hv + hg];

    for (int s = 0; s < STEPS; ++s) {
      const int par = s & 1;
      // phase A: threads 0..511 poll x = h0[s] (tag s+1, replica B);
      //          threads 512..1023 poll hprev = y1[s-1] (tag s). 1 word each.
      if (tid < Hv) {
        const uint64_t* src = h0B + (size_t)(s&(RING-1))*Hv + tid;
        uint32_t want = (uint32_t)(s+1);
        uint64_t a = aload64(src);
        while (tagof(a) != want) a = aload64(src);
        xbuf[par][tid] = valof(a);
      } else {
        if (s == 0) {
          xbuf[0][tid] = h0in[tid];     // h0in[512..1023] = layer-1 h0
        } else {
          const uint64_t* src = y1c + (size_t)((s-1)&(RING-1))*Hv + (tid - Hv);
          uint32_t want = (uint32_t)s;
          uint64_t a = aload64(src);
          while (tagof(a) != want) a = aload64(src);
          xbuf[par][tid] = valof(a);
        }
      }
      __syncthreads();
      // compute: 8 rows x 16 cols per lane
      const float4* xv = (const float4*)(xbuf[par]);
      float4 v0 = xv[lane], v1 = xv[64+lane], v2 = xv[128+lane], v3 = xv[192+lane];
      float acc[8];
#pragma unroll
      for (int r = 0; r < 8; ++r) {
        float a = 0.f;
        a = fmaf(w[r*16+ 0], v0.x, a); a = fmaf(w[r*16+ 1], v0.y, a);
        a = fmaf(w[r*16+ 2], v0.z, a); a = fmaf(w[r*16+ 3], v0.w, a);
        a = fmaf(w[r*16+ 4], v1.x, a); a = fmaf(w[r*16+ 5], v1.y, a);
        a = fmaf(w[r*16+ 6], v1.z, a); a = fmaf(w[r*16+ 7], v1.w, a);
        a = fmaf(w[r*16+ 8], v2.x, a); a = fmaf(w[r*16+ 9], v2.y, a);
        a = fmaf(w[r*16+10], v2.z, a); a = fmaf(w[r*16+11], v2.w, a);
        a = fmaf(w[r*16+12], v3.x, a); a = fmaf(w[r*16+13], v3.y, a);
        a = fmaf(w[r*16+14], v3.z, a); a = fmaf(w[r*16+15], v3.w, a);
        acc[r] = a;
      }
      bfly_halve<8>(acc, 32);
      bfly_halve<4>(acc, 16);
      bfly_halve<2>(acc, 8);
      acc[0] += __shfl_xor(acc[0], 4, 64);
      acc[0] += __shfl_xor(acc[0], 2, 64);
      acc[0] += __shfl_xor(acc[0], 1, 64);   // lane holds row (lane>>3)
      float gi = __shfl(acc[0], 32*jsel + 0,  64);
      float gf = __shfl(acc[0], 32*jsel + 8,  64);
      float gg = __shfl(acc[0], 32*jsel + 16, 64);
      float go = __shfl(acc[0], 32*jsel + 24, 64);
      float cc = sigmf(gf+cgf)*cst + sigmf(gi+cgi)*tanhf(gg+cgg);
      float hh = sigmf(go+cgo)*tanhf(cc);
      cst = cc;
      if (lane < 2) {
        astore64(y1c + (size_t)(s&(RING-1))*Hv + hg, mkword((uint32_t)(s+1), hh));
        ys1[(size_t)s*Hv + hg] = hh;   // plain store for postproc
      }
      if ((s & 511) == 511) {
        __syncthreads();   // drain all waves' ys1 stores
        if (tid == 0) {
          __builtin_amdgcn_fence(__ATOMIC_RELEASE, "agent");
          astore32(iterflag + wg1, (uint32_t)((s >> 9) + 1));
        }
      }
    }
  } else {
    // ================= Postprocess (1024 threads) =================
    const int p = bid - KA - KB;
    for (int r = tid; r < OUTv*Hv; r += 1024) Wout_s[r] = Wout[r];
    for (int h = tid; h < Hv; h += 1024) { gam_s[h] = gamma[h]; bet_s[h] = beta[h]; }
    float bo[OUTv];
#pragma unroll
    for (int o = 0; o < OUTv; ++o) bo[o] = bout[o];
    __syncthreads();

    for (int i = p; i < Tv; i += KPP) {
      const uint32_t tgt = (uint32_t)(i + 1);
      if (tid < 64) {
        for (;;) {
          uint32_t v = aload32(iterflag + (lane & 15));
          if (__all((int)(v >= tgt && v <= (uint32_t)Tv))) break;
          __builtin_amdgcn_s_sleep(16);
        }
      }
      __syncthreads();
      __builtin_amdgcn_fence(__ATOMIC_ACQUIRE, "agent");

      const float* Y = ys1 + (size_t)i * Bv * Hv;

      for (int h = tid; h < Hv; h += 1024) {
        double sum = 0.0, sq = 0.0;
        for (int b = 0; b < Bv; ++b) {
          double v = (double)Y[(size_t)b*Hv + h];
          sum += v; sq += v*v;
        }
        double mu = sum * (1.0/512.0);
        double var = sq * (1.0/512.0) - mu*mu;
        if (var < 0.0) var = 0.0;
        mu_s[h]  = (float)mu;
        isd_s[h] = (float)(1.0 / sqrt(var + 1e-5));
      }
      __syncthreads();

      uint32_t k0, k1;
      threefry2x32(0u, 42u, 0u, (uint32_t)i, k0, k1);

      for (int b = tid; b < Bv; b += 1024) {
        float lg[OUTv];
#pragma unroll
        for (int o = 0; o < OUTv; ++o) lg[o] = 0.f;
        const float* Yb = Y + (size_t)b * Hv;
        for (int h = 0; h < Hv; ++h) {
          float yn = (Yb[h] - mu_s[h]) * isd_s[h] * gam_s[h] + bet_s[h];
          float gv = expf(-yn*yn);
#pragma unroll
          for (int o = 0; o < OUTv; ++o) lg[o] = fmaf(gv, Wout_s[o*Hv + h], lg[o]);
        }
#pragma unroll
        for (int o = 0; o < OUTv; ++o) lg[o] += bo[o];

        int action; float la;
        if (i < 15) {
          float best = -3.0e38f; int bi = 0; float bl = lg[0];
#pragma unroll
          for (int o = 0; o < OUTv; ++o) {
            uint32_t bits = tf_bits32(k0, k1, (uint32_t)(b*12 + o));
            float z = gumbelf(bits) + lg[o];
            if (z > best) { best = z; bi = o; bl = lg[o]; }
          }
          action = bi; la = bl;
        } else {
          float best = -3.0e38f; int bi = 0; float bl = lg[S0v];
#pragma unroll
          for (int o = 0; o < 4; ++o) {
            uint32_t bits = tf_bits32(k0, k1, (uint32_t)(b*4 + o));
            float z = gumbelf(bits) + lg[S0v + o];
            if (z > best) { best = z; bi = o; bl = lg[S0v + o]; }
          }
          action = S0v + bi; la = bl;
        }

        float mx = lg[0];
#pragma unroll
        for (int o = 1; o < OUTv; ++o) mx = fmaxf(mx, lg[o]);
        float se = 0.f;
#pragma unroll
        for (int o = 0; o < OUTv; ++o) se += expf(lg[o] - mx);
        float lp = (la - mx) - logf(se);

        out[i*Bv + b]         = (float)action;
        out[STEPS + i*Bv + b] = lp;
      }
    }
  }
}

extern "C" void kernel_launch(void* const* d_in, const int* in_sizes, int n_in,
                              void* d_out, int out_size, void* d_ws, size_t ws_size,
                              hipStream_t stream) {
  const float* Wih0 = (const float*)d_in[0];
  const float* Whh0 = (const float*)d_in[1];
  const float* b0   = (const float*)d_in[2];
  const float* Wih1 = (const float*)d_in[3];
  const float* Whh1 = (const float*)d_in[4];
  const float* b1   = (const float*)d_in[5];
  const float* gam  = (const float*)d_in[6];
  const float* bet  = (const float*)d_in[7];
  const float* Wout = (const float*)d_in[8];
  const float* bout = (const float*)d_in[9];
  const float* h0   = (const float*)d_in[10];
  const float* c0   = (const float*)d_in[11];

  net_persistent<<<dim3(NBLK), dim3(1024), 0, stream>>>(
      Wih0, Whh0, b0, Wih1, Whh1, b1, gam, bet, Wout, bout, h0, c0,
      (float*)d_out, (uint32_t*)d_ws);
}

// Round 10
// 47477.896 us; speedup vs baseline: 2.8225x; 2.8225x over previous
//
#include <hip/hip_runtime.h>
#include <stdint.h>
#include <math.h>

// Problem constants
#define Bv      512
#define INv     64
#define Hv      512
#define OUTv    12
#define Tv      31
#define S0v     8
#define STEPS   (Tv*Bv)        // 15872 sequential LSTM steps per layer

// Workgroup roles — r8 config (best): 512-thread blocks, 48 LSTM sync domains
#define KA      16             // layer-0 WGs (32 h each, 4 h per wave)
#define KB      32             // layer-1 WGs (16 h each, 2 h per wave)
#define KPP     16             // postproc WGs
#define NBLK    (KA+KB+KPP)    // 64 blocks -> co-resident
#define RING    32             // comm ring depth (power of 2)

// ws layout (bytes), total 32,903,168 (same as r6/r8):
//  [0, 128)       : iterflag u32[32]
//  [4096,   +128K): h0A u64[RING][512]  — read by L0
//  [135168, +128K): h0B u64[RING][512]  — read by L1
//  [266240, +128K): y1c u64[RING][512]  — read by L1 (+ L0 throttle, sparse)
//  [397312, ...)  : ys1 float[STEPS][512]  (plain, fenced per iteration)

// ---------------- threefry2x32 (JAX-exact) ----------------
__device__ __forceinline__ uint32_t rotl32(uint32_t v, int r){ return (v<<r)|(v>>(32-r)); }

__device__ __forceinline__ void threefry2x32(uint32_t k0, uint32_t k1,
                                             uint32_t x0, uint32_t x1,
                                             uint32_t& o0, uint32_t& o1) {
  uint32_t ks2 = k0 ^ k1 ^ 0x1BD11BDAu;
  x0 += k0; x1 += k1;
#define TFR(r) { x0 += x1; x1 = rotl32(x1, r); x1 ^= x0; }
  TFR(13) TFR(15) TFR(26) TFR(6)
  x0 += k1;  x1 += ks2 + 1u;
  TFR(17) TFR(29) TFR(16) TFR(24)
  x0 += ks2; x1 += k0 + 2u;
  TFR(13) TFR(15) TFR(26) TFR(6)
  x0 += k0;  x1 += k1 + 3u;
  TFR(17) TFR(29) TFR(16) TFR(24)
  x0 += k1;  x1 += ks2 + 4u;
  TFR(13) TFR(15) TFR(26) TFR(6)
  x0 += ks2; x1 += k0 + 5u;
#undef TFR
  o0 = x0; o1 = x1;
}

__device__ __forceinline__ uint32_t tf_bits32(uint32_t k0, uint32_t k1, uint32_t j) {
  uint32_t a, b;
  threefry2x32(k0, k1, 0u, j, a, b);
  return a ^ b;
}

__device__ __forceinline__ float u32_to_uniform(uint32_t bits) {
  float f = __uint_as_float(0x3F800000u | (bits >> 9)) - 1.0f;
  const float TINY = 1.17549435e-38f;
  return fmaxf(TINY, f + TINY);
}

__device__ __forceinline__ float gumbelf(uint32_t bits) {
  float u = u32_to_uniform(bits);
  return -logf(-logf(u));
}

__device__ __forceinline__ float sigmf(float x) {
  if (x >= 0.f) { float z = expf(-x); return 1.f/(1.f+z); }
  float z = expf(x); return z/(1.f+z);
}

// Butterfly: halve per-lane row-partials across lanes (xor mask m).
template<int N>
__device__ __forceinline__ void bfly_halve(float* v, int m) {
  int lane = threadIdx.x & 63;
  bool up = (lane & m) != 0;
#pragma unroll
  for (int j = 0; j < N/2; ++j) {
    float send = up ? v[j] : v[j + N/2];
    float recv = __shfl_xor(send, m, 64);
    v[j] = (up ? v[j + N/2] : v[j]) + recv;
  }
}

__device__ __forceinline__ uint64_t aload64(const uint64_t* p){
  return __hip_atomic_load(p, __ATOMIC_RELAXED, __HIP_MEMORY_SCOPE_AGENT);
}
__device__ __forceinline__ void astore64(uint64_t* p, uint64_t v){
  __hip_atomic_store(p, v, __ATOMIC_RELAXED, __HIP_MEMORY_SCOPE_AGENT);
}
__device__ __forceinline__ uint32_t aload32(const uint32_t* p){
  return __hip_atomic_load(p, __ATOMIC_RELAXED, __HIP_MEMORY_SCOPE_AGENT);
}
__device__ __forceinline__ void astore32(uint32_t* p, uint32_t v){
  __hip_atomic_store(p, v, __ATOMIC_RELAXED, __HIP_MEMORY_SCOPE_AGENT);
}
__device__ __forceinline__ uint32_t tagof(uint64_t w){ return (uint32_t)(w>>32); }
__device__ __forceinline__ float    valof(uint64_t w){ return __uint_as_float((uint32_t)w); }
__device__ __forceinline__ uint64_t mkword(uint32_t t, float v){
  return ((uint64_t)t<<32) | (uint64_t)__float_as_uint(v);
}

__global__ __launch_bounds__(512, 1)
void net_persistent(const float* __restrict__ Wih0, const float* __restrict__ Whh0,
                    const float* __restrict__ b0,
                    const float* __restrict__ Wih1, const float* __restrict__ Whh1,
                    const float* __restrict__ b1,
                    const float* __restrict__ gamma, const float* __restrict__ beta,
                    const float* __restrict__ Wout, const float* __restrict__ bout,
                    const float* __restrict__ h0in, const float* __restrict__ c0in,
                    float* __restrict__ out, uint32_t* __restrict__ wsu)
{
  uint32_t* iterflag = wsu;                              // [32]
  uint64_t* h0A = (uint64_t*)((char*)wsu + 4096);
  uint64_t* h0B = (uint64_t*)((char*)wsu + 4096 + (size_t)RING*Hv*8);
  uint64_t* y1c = (uint64_t*)((char*)wsu + 4096 + (size_t)2*RING*Hv*8);
  float*    ys1 = (float*)((char*)wsu + 4096 + (size_t)3*RING*Hv*8);

  const int bid  = blockIdx.x;
  const int tid  = threadIdx.x;
  const int wave = tid >> 6;
  const int lane = tid & 63;

  __shared__ float hbuf[2][Hv];      // L0 input double-buffer
  __shared__ float xbuf[2][2*Hv];    // L1 input double-buffer [x | hprev]
  __shared__ float Wout_s[OUTv*Hv];
  __shared__ float mu_s[Hv], isd_s[Hv], gam_s[Hv], bet_s[Hv];

  if (bid < KA) {
    // ================= Layer 0 (autonomous: x = ones folded) =================
    // 16 WGs x 512 threads; wave (0..7) owns 4 h-indices.
    const int hbase = bid*32;
    float w[128];
#pragma unroll
    for (int jl = 0; jl < 4; ++jl)
#pragma unroll
      for (int g = 0; g < 4; ++g) {
        int r = jl*4 + g;
        const float* rp = Whh0 + (size_t)(g*Hv + hbase + wave*4 + jl)*Hv;
#pragma unroll
        for (int k = 0; k < 2; ++k) {
          float4 q = *(const float4*)(rp + k*256 + lane*4);
          w[r*8+k*4+0]=q.x; w[r*8+k*4+1]=q.y; w[r*8+k*4+2]=q.z; w[r*8+k*4+3]=q.w;
        }
      }
    // per-lane gate constants (x = ones folded) + c-state for h-index lane&3
    const int jsel = lane & 3;
    const int hg = hbase + wave*4 + jsel;
    float cgi, cgf, cgg, cgo;
    {
      float s0=b0[0*Hv+hg], s1=b0[1*Hv+hg], s2=b0[2*Hv+hg], s3=b0[3*Hv+hg];
      for (int k = 0; k < INv; ++k) {
        s0 += Wih0[(size_t)(0*Hv+hg)*INv+k];
        s1 += Wih0[(size_t)(1*Hv+hg)*INv+k];
        s2 += Wih0[(size_t)(2*Hv+hg)*INv+k];
        s3 += Wih0[(size_t)(3*Hv+hg)*INv+k];
      }
      cgi=s0; cgf=s1; cgg=s2; cgo=s3;
    }
    float cst = c0in[hg];

    for (int s = 0; s < STEPS; ++s) {
      const int par = s & 1;
      // ring throttle every 16 steps: require L1 consumed h0 tag >= s-16
      // before overwriting slots s-32..s-17 (L1 progress via y1c tags).
      if ((s & 15) == 0 && s >= 32) {
        const uint64_t* tp = y1c + (size_t)((s-17)&(RING-1))*Hv + lane*8;
        uint32_t need = (uint32_t)(s - 16);
        for (;;) {
          uint32_t t = tagof(aload64(tp));
          if (__all((int)(t >= need && t <= (uint32_t)STEPS))) break;
          __builtin_amdgcn_s_sleep(1);
        }
      }
      // phase A: poll previous h into LDS — 1 word per thread, depth-2 pipelined
      {
        int idx = tid;
        if (s == 0) {
          hbuf[0][idx] = h0in[idx];
        } else {
          const uint64_t* src = h0A + (size_t)((s-1)&(RING-1))*Hv + idx;
          uint32_t want = (uint32_t)s;
          uint64_t a  = aload64(src);
          uint64_t a2 = aload64(src);
          while (tagof(a) != want) { a = a2; a2 = aload64(src); }
          hbuf[par][idx] = valof(a);
        }
      }
      __syncthreads();
      // compute: 16 rows x 8 cols per lane
      const float4* hv = (const float4*)(hbuf[par]);
      float4 vA = hv[lane], vB = hv[64 + lane];
      float acc[16];
#pragma unroll
      for (int r = 0; r < 16; ++r) {
        float a = 0.f;
        a = fmaf(w[r*8+0], vA.x, a); a = fmaf(w[r*8+1], vA.y, a);
        a = fmaf(w[r*8+2], vA.z, a); a = fmaf(w[r*8+3], vA.w, a);
        a = fmaf(w[r*8+4], vB.x, a); a = fmaf(w[r*8+5], vB.y, a);
        a = fmaf(w[r*8+6], vB.z, a); a = fmaf(w[r*8+7], vB.w, a);
        acc[r] = a;
      }
      bfly_halve<16>(acc, 32);
      bfly_halve<8>(acc, 16);
      bfly_halve<4>(acc, 8);
      bfly_halve<2>(acc, 4);
      acc[0] += __shfl_xor(acc[0], 2, 64);
      acc[0] += __shfl_xor(acc[0], 1, 64);   // lane holds row (lane>>2)
      // every lane gathers the 4 gates of h-index jsel
      float gi = __shfl(acc[0], 16*jsel + 0,  64);
      float gf = __shfl(acc[0], 16*jsel + 4,  64);
      float gg = __shfl(acc[0], 16*jsel + 8,  64);
      float go = __shfl(acc[0], 16*jsel + 12, 64);
      float cc = sigmf(gf+cgf)*cst + sigmf(gi+cgi)*tanhf(gg+cgg);
      float hh = sigmf(go+cgo)*tanhf(cc);
      cst = cc;
      if (lane < 8) {   // lanes 0-3 -> replica A (L0 readers); 4-7 -> B (L1 readers)
        uint64_t* dst = (lane < 4) ? h0A : h0B;
        astore64(dst + (size_t)(s&(RING-1))*Hv + hg, mkword((uint32_t)(s+1), hh));
      }
    }
  } else if (bid < KA + KB) {
    // ================= Layer 1 =================
    // 32 WGs x 512 threads; wave (0..7) owns 2 h-indices.
    const int wg1 = bid - KA;
    const int hbase = wg1*16;
    float w[128];
#pragma unroll
    for (int jl = 0; jl < 2; ++jl)
#pragma unroll
      for (int g = 0; g < 4; ++g) {
        int r = jl*4 + g;
        int row = g*Hv + hbase + wave*2 + jl;
#pragma unroll
        for (int k = 0; k < 4; ++k) {
          int col = k*256 + lane*4;
          const float* M = (col < Hv) ? (Wih1 + (size_t)row*Hv + col)
                                      : (Whh1 + (size_t)row*Hv + (col - Hv));
          float4 q = *(const float4*)M;
          w[r*16+k*4+0]=q.x; w[r*16+k*4+1]=q.y; w[r*16+k*4+2]=q.z; w[r*16+k*4+3]=q.w;
        }
      }
    const int jsel = lane & 1;
    const int hg = hbase + wave*2 + jsel;
    float cgi = b1[0*Hv+hg], cgf = b1[1*Hv+hg],
          cgg = b1[2*Hv+hg], cgo = b1[3*Hv+hg];
    float cst = c0in[Hv + hg];

    for (int s = 0; s < STEPS; ++s) {
      const int par = s & 1;
      // phase A: poll x = h0[s] (tag s+1, replica B) and hprev = y1[s-1] (tag s)
      // 2 words per thread, depth-2 pipelined.
      {
        int j0 = tid*2;
        if (j0 < Hv) {
          const uint64_t* src = h0B + (size_t)(s&(RING-1))*Hv + j0;
          uint32_t want = (uint32_t)(s+1);
          uint64_t a  = aload64(src), b  = aload64(src+1);
          uint64_t a2 = aload64(src), b2 = aload64(src+1);
          while (tagof(a) != want || tagof(b) != want) {
            a = a2; b = b2;
            a2 = aload64(src); b2 = aload64(src+1);
          }
          xbuf[par][j0] = valof(a); xbuf[par][j0+1] = valof(b);
        } else {
          if (s == 0) {
            xbuf[0][j0]   = h0in[j0];     // h0in[512..1023] = layer-1 h0
            xbuf[0][j0+1] = h0in[j0+1];
          } else {
            const uint64_t* src = y1c + (size_t)((s-1)&(RING-1))*Hv + (j0 - Hv);
            uint32_t want = (uint32_t)s;
            uint64_t a  = aload64(src), b  = aload64(src+1);
            uint64_t a2 = aload64(src), b2 = aload64(src+1);
            while (tagof(a) != want || tagof(b) != want) {
              a = a2; b = b2;
              a2 = aload64(src); b2 = aload64(src+1);
            }
            xbuf[par][j0] = valof(a); xbuf[par][j0+1] = valof(b);
          }
        }
      }
      __syncthreads();
      // compute: 8 rows x 16 cols per lane
      const float4* xv = (const float4*)(xbuf[par]);
      float4 v0 = xv[lane], v1 = xv[64+lane], v2 = xv[128+lane], v3 = xv[192+lane];
      float acc[8];
#pragma unroll
      for (int r = 0; r < 8; ++r) {
        float a = 0.f;
        a = fmaf(w[r*16+ 0], v0.x, a); a = fmaf(w[r*16+ 1], v0.y, a);
        a = fmaf(w[r*16+ 2], v0.z, a); a = fmaf(w[r*16+ 3], v0.w, a);
        a = fmaf(w[r*16+ 4], v1.x, a); a = fmaf(w[r*16+ 5], v1.y, a);
        a = fmaf(w[r*16+ 6], v1.z, a); a = fmaf(w[r*16+ 7], v1.w, a);
        a = fmaf(w[r*16+ 8], v2.x, a); a = fmaf(w[r*16+ 9], v2.y, a);
        a = fmaf(w[r*16+10], v2.z, a); a = fmaf(w[r*16+11], v2.w, a);
        a = fmaf(w[r*16+12], v3.x, a); a = fmaf(w[r*16+13], v3.y, a);
        a = fmaf(w[r*16+14], v3.z, a); a = fmaf(w[r*16+15], v3.w, a);
        acc[r] = a;
      }
      bfly_halve<8>(acc, 32);
      bfly_halve<4>(acc, 16);
      bfly_halve<2>(acc, 8);
      acc[0] += __shfl_xor(acc[0], 4, 64);
      acc[0] += __shfl_xor(acc[0], 2, 64);
      acc[0] += __shfl_xor(acc[0], 1, 64);   // lane holds row (lane>>3)
      float gi = __shfl(acc[0], 32*jsel + 0,  64);
      float gf = __shfl(acc[0], 32*jsel + 8,  64);
      float gg = __shfl(acc[0], 32*jsel + 16, 64);
      float go = __shfl(acc[0], 32*jsel + 24, 64);
      float cc = sigmf(gf+cgf)*cst + sigmf(gi+cgi)*tanhf(gg+cgg);
      float hh = sigmf(go+cgo)*tanhf(cc);
      cst = cc;
      if (lane < 2) {
        astore64(y1c + (size_t)(s&(RING-1))*Hv + hg, mkword((uint32_t)(s+1), hh));
        ys1[(size_t)s*Hv + hg] = hh;   // plain store for postproc
      }
      if ((s & 511) == 511) {
        __syncthreads();   // drain all waves' ys1 stores
        if (tid == 0) {
          __builtin_amdgcn_fence(__ATOMIC_RELEASE, "agent");
          astore32(iterflag + wg1, (uint32_t)((s >> 9) + 1));
        }
      }
    }
  } else {
    // ================= Postprocess (512 threads) =================
    const int p = bid - KA - KB;
    for (int r = tid; r < OUTv*Hv; r += 512) Wout_s[r] = Wout[r];
    for (int h = tid; h < Hv; h += 512) { gam_s[h] = gamma[h]; bet_s[h] = beta[h]; }
    float bo[OUTv];
#pragma unroll
    for (int o = 0; o < OUTv; ++o) bo[o] = bout[o];
    __syncthreads();

    for (int i = p; i < Tv; i += KPP) {
      const uint32_t tgt = (uint32_t)(i + 1);
      if (tid < 64) {
        for (;;) {
          uint32_t v = aload32(iterflag + (lane & 31));
          if (__all((int)(v >= tgt && v <= (uint32_t)Tv))) break;
          __builtin_amdgcn_s_sleep(16);
        }
      }
      __syncthreads();
      __builtin_amdgcn_fence(__ATOMIC_ACQUIRE, "agent");

      const float* Y = ys1 + (size_t)i * Bv * Hv;

      for (int h = tid; h < Hv; h += 512) {
        double sum = 0.0, sq = 0.0;
        for (int b = 0; b < Bv; ++b) {
          double v = (double)Y[(size_t)b*Hv + h];
          sum += v; sq += v*v;
        }
        double mu = sum * (1.0/512.0);
        double var = sq * (1.0/512.0) - mu*mu;
        if (var < 0.0) var = 0.0;
        mu_s[h]  = (float)mu;
        isd_s[h] = (float)(1.0 / sqrt(var + 1e-5));
      }
      __syncthreads();

      uint32_t k0, k1;
      threefry2x32(0u, 42u, 0u, (uint32_t)i, k0, k1);

      for (int b = tid; b < Bv; b += 512) {
        float lg[OUTv];
#pragma unroll
        for (int o = 0; o < OUTv; ++o) lg[o] = 0.f;
        const float* Yb = Y + (size_t)b * Hv;
        for (int h = 0; h < Hv; ++h) {
          float yn = (Yb[h] - mu_s[h]) * isd_s[h] * gam_s[h] + bet_s[h];
          float gv = expf(-yn*yn);
#pragma unroll
          for (int o = 0; o < OUTv; ++o) lg[o] = fmaf(gv, Wout_s[o*Hv + h], lg[o]);
        }
#pragma unroll
        for (int o = 0; o < OUTv; ++o) lg[o] += bo[o];

        int action; float la;
        if (i < 15) {
          float best = -3.0e38f; int bi = 0; float bl = lg[0];
#pragma unroll
          for (int o = 0; o < OUTv; ++o) {
            uint32_t bits = tf_bits32(k0, k1, (uint32_t)(b*12 + o));
            float z = gumbelf(bits) + lg[o];
            if (z > best) { best = z; bi = o; bl = lg[o]; }
          }
          action = bi; la = bl;
        } else {
          float best = -3.0e38f; int bi = 0; float bl = lg[S0v];
#pragma unroll
          for (int o = 0; o < 4; ++o) {
            uint32_t bits = tf_bits32(k0, k1, (uint32_t)(b*4 + o));
            float z = gumbelf(bits) + lg[S0v + o];
            if (z > best) { best = z; bi = o; bl = lg[S0v + o]; }
          }
          action = S0v + bi; la = bl;
        }

        float mx = lg[0];
#pragma unroll
        for (int o = 1; o < OUTv; ++o) mx = fmaxf(mx, lg[o]);
        float se = 0.f;
#pragma unroll
        for (int o = 0; o < OUTv; ++o) se += expf(lg[o] - mx);
        float lp = (la - mx) - logf(se);

        out[i*Bv + b]         = (float)action;
        out[STEPS + i*Bv + b] = lp;
      }
    }
  }
}

extern "C" void kernel_launch(void* const* d_in, const int* in_sizes, int n_in,
                              void* d_out, int out_size, void* d_ws, size_t ws_size,
                              hipStream_t stream) {
  const float* Wih0 = (const float*)d_in[0];
  const float* Whh0 = (const float*)d_in[1];
  const float* b0   = (const float*)d_in[2];
  const float* Wih1 = (const float*)d_in[3];
  const float* Whh1 = (const float*)d_in[4];
  const float* b1   = (const float*)d_in[5];
  const float* gam  = (const float*)d_in[6];
  const float* bet  = (const float*)d_in[7];
  const float* Wout = (const float*)d_in[8];
  const float* bout = (const float*)d_in[9];
  const float* h0   = (const float*)d_in[10];
  const float* c0   = (const float*)d_in[11];

  net_persistent<<<dim3(NBLK), dim3(512), 0, stream>>>(
      Wih0, Whh0, b0, Wih1, Whh1, b1, gam, bet, Wout, bout, h0, c0,
      (float*)d_out, (uint32_t*)d_ws);
}

// Round 11
// 41113.480 us; speedup vs baseline: 3.2594x; 1.1548x over previous
//
#include <hip/hip_runtime.h>
#include <stdint.h>
#include <math.h>

// Problem constants
#define Bv      512
#define INv     64
#define Hv      512
#define OUTv    12
#define Tv      31
#define S0v     8
#define STEPS   (Tv*Bv)        // 15872 sequential LSTM steps per layer

// Workgroup roles — r8 config (champion): 512-thread blocks, 48 LSTM sync domains
#define KA      16             // layer-0 WGs (32 h each, 4 h per wave)
#define KB      32             // layer-1 WGs (16 h each, 2 h per wave)
#define KPP     16             // postproc WGs
#define NBLK    (KA+KB+KPP)    // 64 blocks -> co-resident
#define RING    32             // comm ring depth (power of 2)

// ws layout (bytes), total 32,903,168:
//  [0, 128)       : iterflag u32[32]
//  [4096,   +128K): h0A u64[RING][512]  — read by L0
//  [135168, +128K): h0B u64[RING][512]  — read by L1
//  [266240, +128K): y1c u64[RING][512]  — read by L1 (+ L0 throttle, sparse)
//  [397312, ...)  : ys1 float[STEPS][512]  (plain, fenced per iteration)

// ---------------- threefry2x32 (JAX-exact) ----------------
__device__ __forceinline__ uint32_t rotl32(uint32_t v, int r){ return (v<<r)|(v>>(32-r)); }

__device__ __forceinline__ void threefry2x32(uint32_t k0, uint32_t k1,
                                             uint32_t x0, uint32_t x1,
                                             uint32_t& o0, uint32_t& o1) {
  uint32_t ks2 = k0 ^ k1 ^ 0x1BD11BDAu;
  x0 += k0; x1 += k1;
#define TFR(r) { x0 += x1; x1 = rotl32(x1, r); x1 ^= x0; }
  TFR(13) TFR(15) TFR(26) TFR(6)
  x0 += k1;  x1 += ks2 + 1u;
  TFR(17) TFR(29) TFR(16) TFR(24)
  x0 += ks2; x1 += k0 + 2u;
  TFR(13) TFR(15) TFR(26) TFR(6)
  x0 += k0;  x1 += k1 + 3u;
  TFR(17) TFR(29) TFR(16) TFR(24)
  x0 += k1;  x1 += ks2 + 4u;
  TFR(13) TFR(15) TFR(26) TFR(6)
  x0 += ks2; x1 += k0 + 5u;
#undef TFR
  o0 = x0; o1 = x1;
}

__device__ __forceinline__ uint32_t tf_bits32(uint32_t k0, uint32_t k1, uint32_t j) {
  uint32_t a, b;
  threefry2x32(k0, k1, 0u, j, a, b);
  return a ^ b;
}

__device__ __forceinline__ float u32_to_uniform(uint32_t bits) {
  float f = __uint_as_float(0x3F800000u | (bits >> 9)) - 1.0f;
  const float TINY = 1.17549435e-38f;
  return fmaxf(TINY, f + TINY);
}

__device__ __forceinline__ float gumbelf(uint32_t bits) {
  float u = u32_to_uniform(bits);
  return -logf(-logf(u));
}

__device__ __forceinline__ float sigmf(float x) {
  if (x >= 0.f) { float z = expf(-x); return 1.f/(1.f+z); }
  float z = expf(x); return z/(1.f+z);
}

// Butterfly: halve per-lane row-partials across lanes (xor mask m).
template<int N>
__device__ __forceinline__ void bfly_halve(float* v, int m) {
  int lane = threadIdx.x & 63;
  bool up = (lane & m) != 0;
#pragma unroll
  for (int j = 0; j < N/2; ++j) {
    float send = up ? v[j] : v[j + N/2];
    float recv = __shfl_xor(send, m, 64);
    v[j] = (up ? v[j + N/2] : v[j]) + recv;
  }
}

__device__ __forceinline__ uint64_t aload64(const uint64_t* p){
  return __hip_atomic_load(p, __ATOMIC_RELAXED, __HIP_MEMORY_SCOPE_AGENT);
}
__device__ __forceinline__ void astore64(uint64_t* p, uint64_t v){
  __hip_atomic_store(p, v, __ATOMIC_RELAXED, __HIP_MEMORY_SCOPE_AGENT);
}
__device__ __forceinline__ uint32_t aload32(const uint32_t* p){
  return __hip_atomic_load(p, __ATOMIC_RELAXED, __HIP_MEMORY_SCOPE_AGENT);
}
__device__ __forceinline__ void astore32(uint32_t* p, uint32_t v){
  __hip_atomic_store(p, v, __ATOMIC_RELAXED, __HIP_MEMORY_SCOPE_AGENT);
}
__device__ __forceinline__ uint32_t tagof(uint64_t w){ return (uint32_t)(w>>32); }
__device__ __forceinline__ float    valof(uint64_t w){ return __uint_as_float((uint32_t)w); }
__device__ __forceinline__ uint64_t mkword(uint32_t t, float v){
  return ((uint64_t)t<<32) | (uint64_t)__float_as_uint(v);
}

__global__ __launch_bounds__(512, 1)
void net_persistent(const float* __restrict__ Wih0, const float* __restrict__ Whh0,
                    const float* __restrict__ b0,
                    const float* __restrict__ Wih1, const float* __restrict__ Whh1,
                    const float* __restrict__ b1,
                    const float* __restrict__ gamma, const float* __restrict__ beta,
                    const float* __restrict__ Wout, const float* __restrict__ bout,
                    const float* __restrict__ h0in, const float* __restrict__ c0in,
                    float* __restrict__ out, uint32_t* __restrict__ wsu)
{
  uint32_t* iterflag = wsu;                              // [32]
  uint64_t* h0A = (uint64_t*)((char*)wsu + 4096);
  uint64_t* h0B = (uint64_t*)((char*)wsu + 4096 + (size_t)RING*Hv*8);
  uint64_t* y1c = (uint64_t*)((char*)wsu + 4096 + (size_t)2*RING*Hv*8);
  float*    ys1 = (float*)((char*)wsu + 4096 + (size_t)3*RING*Hv*8);

  const int bid  = blockIdx.x;
  const int tid  = threadIdx.x;
  const int wave = tid >> 6;
  const int lane = tid & 63;

  __shared__ float hbuf[2][Hv];      // L0 input double-buffer
  __shared__ float xbuf[2][2*Hv];    // L1 input double-buffer [x | hprev]
  __shared__ float Wout_s[OUTv*Hv];
  __shared__ float mu_s[Hv], isd_s[Hv], gam_s[Hv], bet_s[Hv];

  if (bid < KA) {
    // ================= Layer 0 (autonomous: x = ones folded) =================
    // 16 WGs x 512 threads; wave (0..7) owns 4 h-indices.
    const int hbase = bid*32;
    float w[128];
#pragma unroll
    for (int jl = 0; jl < 4; ++jl)
#pragma unroll
      for (int g = 0; g < 4; ++g) {
        int r = jl*4 + g;
        const float* rp = Whh0 + (size_t)(g*Hv + hbase + wave*4 + jl)*Hv;
#pragma unroll
        for (int k = 0; k < 2; ++k) {
          float4 q = *(const float4*)(rp + k*256 + lane*4);
          w[r*8+k*4+0]=q.x; w[r*8+k*4+1]=q.y; w[r*8+k*4+2]=q.z; w[r*8+k*4+3]=q.w;
        }
      }
    // per-lane gate constants (x = ones folded) + c-state for h-index lane&3
    const int jsel = lane & 3;
    const int hg = hbase + wave*4 + jsel;
    float cgi, cgf, cgg, cgo;
    {
      float s0=b0[0*Hv+hg], s1=b0[1*Hv+hg], s2=b0[2*Hv+hg], s3=b0[3*Hv+hg];
      for (int k = 0; k < INv; ++k) {
        s0 += Wih0[(size_t)(0*Hv+hg)*INv+k];
        s1 += Wih0[(size_t)(1*Hv+hg)*INv+k];
        s2 += Wih0[(size_t)(2*Hv+hg)*INv+k];
        s3 += Wih0[(size_t)(3*Hv+hg)*INv+k];
      }
      cgi=s0; cgf=s1; cgg=s2; cgo=s3;
    }
    float cst = c0in[hg];

    for (int s = 0; s < STEPS; ++s) {
      const int par = s & 1;
      // ring throttle every 16 steps: require L1 consumed h0 tag >= s-16
      // before overwriting slots s-32..s-17 (L1 progress via y1c tags).
      if ((s & 15) == 0 && s >= 32) {
        const uint64_t* tp = y1c + (size_t)((s-17)&(RING-1))*Hv + lane*8;
        uint32_t need = (uint32_t)(s - 16);
        for (;;) {
          uint32_t t = tagof(aload64(tp));
          if (__all((int)(t >= need && t <= (uint32_t)STEPS))) break;
          __builtin_amdgcn_s_sleep(1);
        }
      }
      // phase A: poll previous h into LDS — 1 word per thread
      {
        int idx = tid;
        if (s == 0) {
          hbuf[0][idx] = h0in[idx];
        } else {
          const uint64_t* src = h0A + (size_t)((s-1)&(RING-1))*Hv + idx;
          uint32_t want = (uint32_t)s;
          uint64_t a = aload64(src);
          while (tagof(a) != want) a = aload64(src);
          hbuf[par][idx] = valof(a);
        }
      }
      __syncthreads();
      // compute: 16 rows x 8 cols per lane
      const float4* hv = (const float4*)(hbuf[par]);
      float4 vA = hv[lane], vB = hv[64 + lane];
      float acc[16];
#pragma unroll
      for (int r = 0; r < 16; ++r) {
        float a = 0.f;
        a = fmaf(w[r*8+0], vA.x, a); a = fmaf(w[r*8+1], vA.y, a);
        a = fmaf(w[r*8+2], vA.z, a); a = fmaf(w[r*8+3], vA.w, a);
        a = fmaf(w[r*8+4], vB.x, a); a = fmaf(w[r*8+5], vB.y, a);
        a = fmaf(w[r*8+6], vB.z, a); a = fmaf(w[r*8+7], vB.w, a);
        acc[r] = a;
      }
      bfly_halve<16>(acc, 32);
      bfly_halve<8>(acc, 16);
      bfly_halve<4>(acc, 8);
      bfly_halve<2>(acc, 4);
      acc[0] += __shfl_xor(acc[0], 2, 64);
      acc[0] += __shfl_xor(acc[0], 1, 64);   // lane holds row (lane>>2)
      // every lane gathers the 4 gates of h-index jsel
      float gi = __shfl(acc[0], 16*jsel + 0,  64);
      float gf = __shfl(acc[0], 16*jsel + 4,  64);
      float gg = __shfl(acc[0], 16*jsel + 8,  64);
      float go = __shfl(acc[0], 16*jsel + 12, 64);
      float cc = sigmf(gf+cgf)*cst + sigmf(gi+cgi)*tanhf(gg+cgg);
      float hh = sigmf(go+cgo)*tanhf(cc);
      cst = cc;
      if (lane < 8) {   // lanes 0-3 -> replica A (L0 readers); 4-7 -> B (L1 readers)
        uint64_t* dst = (lane < 4) ? h0A : h0B;
        astore64(dst + (size_t)(s&(RING-1))*Hv + hg, mkword((uint32_t)(s+1), hh));
      }
    }
  } else if (bid < KA + KB) {
    // ================= Layer 1 =================
    // 32 WGs x 512 threads; wave (0..7) owns 2 h-indices.
    const int wg1 = bid - KA;
    const int hbase = wg1*16;
    float w[128];
#pragma unroll
    for (int jl = 0; jl < 2; ++jl)
#pragma unroll
      for (int g = 0; g < 4; ++g) {
        int r = jl*4 + g;
        int row = g*Hv + hbase + wave*2 + jl;
#pragma unroll
        for (int k = 0; k < 4; ++k) {
          int col = k*256 + lane*4;
          const float* M = (col < Hv) ? (Wih1 + (size_t)row*Hv + col)
                                      : (Whh1 + (size_t)row*Hv + (col - Hv));
          float4 q = *(const float4*)M;
          w[r*16+k*4+0]=q.x; w[r*16+k*4+1]=q.y; w[r*16+k*4+2]=q.z; w[r*16+k*4+3]=q.w;
        }
      }
    const int jsel = lane & 1;
    const int hg = hbase + wave*2 + jsel;
    float cgi = b1[0*Hv+hg], cgf = b1[1*Hv+hg],
          cgg = b1[2*Hv+hg], cgo = b1[3*Hv+hg];
    float cst = c0in[Hv + hg];

    for (int s = 0; s < STEPS; ++s) {
      const int par = s & 1;
      // phase A: poll x = h0[s] (tag s+1, replica B) and hprev = y1[s-1] (tag s)
      // 2 words per thread: threads 0..255 cover x, 256..511 cover hprev.
      {
        int j0 = tid*2;
        if (j0 < Hv) {
          const uint64_t* src = h0B + (size_t)(s&(RING-1))*Hv + j0;
          uint32_t want = (uint32_t)(s+1);
          uint64_t a = aload64(src), b2 = aload64(src+1);
          while (tagof(a) != want || tagof(b2) != want) {
            a = aload64(src); b2 = aload64(src+1);
          }
          xbuf[par][j0] = valof(a); xbuf[par][j0+1] = valof(b2);
        } else {
          if (s == 0) {
            xbuf[0][j0]   = h0in[j0];     // h0in[512..1023] = layer-1 h0
            xbuf[0][j0+1] = h0in[j0+1];
          } else {
            const uint64_t* src = y1c + (size_t)((s-1)&(RING-1))*Hv + (j0 - Hv);
            uint32_t want = (uint32_t)s;
            uint64_t a = aload64(src), b2 = aload64(src+1);
            while (tagof(a) != want || tagof(b2) != want) {
              a = aload64(src); b2 = aload64(src+1);
            }
            xbuf[par][j0] = valof(a); xbuf[par][j0+1] = valof(b2);
          }
        }
      }
      __syncthreads();
      // compute: 8 rows x 16 cols per lane
      const float4* xv = (const float4*)(xbuf[par]);
      float4 v0 = xv[lane], v1 = xv[64+lane], v2 = xv[128+lane], v3 = xv[192+lane];
      float acc[8];
#pragma unroll
      for (int r = 0; r < 8; ++r) {
        float a = 0.f;
        a = fmaf(w[r*16+ 0], v0.x, a); a = fmaf(w[r*16+ 1], v0.y, a);
        a = fmaf(w[r*16+ 2], v0.z, a); a = fmaf(w[r*16+ 3], v0.w, a);
        a = fmaf(w[r*16+ 4], v1.x, a); a = fmaf(w[r*16+ 5], v1.y, a);
        a = fmaf(w[r*16+ 6], v1.z, a); a = fmaf(w[r*16+ 7], v1.w, a);
        a = fmaf(w[r*16+ 8], v2.x, a); a = fmaf(w[r*16+ 9], v2.y, a);
        a = fmaf(w[r*16+10], v2.z, a); a = fmaf(w[r*16+11], v2.w, a);
        a = fmaf(w[r*16+12], v3.x, a); a = fmaf(w[r*16+13], v3.y, a);
        a = fmaf(w[r*16+14], v3.z, a); a = fmaf(w[r*16+15], v3.w, a);
        acc[r] = a;
      }
      bfly_halve<8>(acc, 32);
      bfly_halve<4>(acc, 16);
      bfly_halve<2>(acc, 8);
      acc[0] += __shfl_xor(acc[0], 4, 64);
      acc[0] += __shfl_xor(acc[0], 2, 64);
      acc[0] += __shfl_xor(acc[0], 1, 64);   // lane holds row (lane>>3)
      float gi = __shfl(acc[0], 32*jsel + 0,  64);
      float gf = __shfl(acc[0], 32*jsel + 8,  64);
      float gg = __shfl(acc[0], 32*jsel + 16, 64);
      float go = __shfl(acc[0], 32*jsel + 24, 64);
      float cc = sigmf(gf+cgf)*cst + sigmf(gi+cgi)*tanhf(gg+cgg);
      float hh = sigmf(go+cgo)*tanhf(cc);
      cst = cc;
      if (lane < 2) {
        astore64(y1c + (size_t)(s&(RING-1))*Hv + hg, mkword((uint32_t)(s+1), hh));
        ys1[(size_t)s*Hv + hg] = hh;   // plain store for postproc
      }
      if ((s & 511) == 511) {
        __syncthreads();   // drain all waves' ys1 stores
        if (tid == 0) {
          __builtin_amdgcn_fence(__ATOMIC_RELEASE, "agent");
          astore32(iterflag + wg1, (uint32_t)((s >> 9) + 1));
        }
      }
    }
  } else {
    // ================= Postprocess (512 threads) =================
    const int p = bid - KA - KB;
    for (int r = tid; r < OUTv*Hv; r += 512) Wout_s[r] = Wout[r];
    for (int h = tid; h < Hv; h += 512) { gam_s[h] = gamma[h]; bet_s[h] = beta[h]; }
    float bo[OUTv];
#pragma unroll
    for (int o = 0; o < OUTv; ++o) bo[o] = bout[o];
    __syncthreads();

    for (int i = p; i < Tv; i += KPP) {
      const uint32_t tgt = (uint32_t)(i + 1);
      if (tid < 64) {
        for (;;) {
          uint32_t v = aload32(iterflag + (lane & 31));
          if (__all((int)(v >= tgt && v <= (uint32_t)Tv))) break;
          __builtin_amdgcn_s_sleep(16);
        }
      }
      __syncthreads();
      __builtin_amdgcn_fence(__ATOMIC_ACQUIRE, "agent");

      const float* Y = ys1 + (size_t)i * Bv * Hv;

      for (int h = tid; h < Hv; h += 512) {
        double sum = 0.0, sq = 0.0;
        for (int b = 0; b < Bv; ++b) {
          double v = (double)Y[(size_t)b*Hv + h];
          sum += v; sq += v*v;
        }
        double mu = sum * (1.0/512.0);
        double var = sq * (1.0/512.0) - mu*mu;
        if (var < 0.0) var = 0.0;
        mu_s[h]  = (float)mu;
        isd_s[h] = (float)(1.0 / sqrt(var + 1e-5));
      }
      __syncthreads();

      uint32_t k0, k1;
      threefry2x32(0u, 42u, 0u, (uint32_t)i, k0, k1);

      for (int b = tid; b < Bv; b += 512) {
        float lg[OUTv];
#pragma unroll
        for (int o = 0; o < OUTv; ++o) lg[o] = 0.f;
        const float* Yb = Y + (size_t)b * Hv;
        for (int h = 0; h < Hv; ++h) {
          float yn = (Yb[h] - mu_s[h]) * isd_s[h] * gam_s[h] + bet_s[h];
          float gv = expf(-yn*yn);
#pragma unroll
          for (int o = 0; o < OUTv; ++o) lg[o] = fmaf(gv, Wout_s[o*Hv + h], lg[o]);
        }
#pragma unroll
        for (int o = 0; o < OUTv; ++o) lg[o] += bo[o];

        int action; float la;
        if (i < 15) {
          float best = -3.0e38f; int bi = 0; float bl = lg[0];
#pragma unroll
          for (int o = 0; o < OUTv; ++o) {
            uint32_t bits = tf_bits32(k0, k1, (uint32_t)(b*12 + o));
            float z = gumbelf(bits) + lg[o];
            if (z > best) { best = z; bi = o; bl = lg[o]; }
          }
          action = bi; la = bl;
        } else {
          float best = -3.0e38f; int bi = 0; float bl = lg[S0v];
#pragma unroll
          for (int o = 0; o < 4; ++o) {
            uint32_t bits = tf_bits32(k0, k1, (uint32_t)(b*4 + o));
            float z = gumbelf(bits) + lg[S0v + o];
            if (z > best) { best = z; bi = o; bl = lg[S0v + o]; }
          }
          action = S0v + bi; la = bl;
        }

        float mx = lg[0];
#pragma unroll
        for (int o = 1; o < OUTv; ++o) mx = fmaxf(mx, lg[o]);
        float se = 0.f;
#pragma unroll
        for (int o = 0; o < OUTv; ++o) se += expf(lg[o] - mx);
        float lp = (la - mx) - logf(se);

        out[i*Bv + b]         = (float)action;
        out[STEPS + i*Bv + b] = lp;
      }
    }
  }
}

extern "C" void kernel_launch(void* const* d_in, const int* in_sizes, int n_in,
                              void* d_out, int out_size, void* d_ws, size_t ws_size,
                              hipStream_t stream) {
  const float* Wih0 = (const float*)d_in[0];
  const float* Whh0 = (const float*)d_in[1];
  const float* b0   = (const float*)d_in[2];
  const float* Wih1 = (const float*)d_in[3];
  const float* Whh1 = (const float*)d_in[4];
  const float* b1   = (const float*)d_in[5];
  const float* gam  = (const float*)d_in[6];
  const float* bet  = (const float*)d_in[7];
  const float* Wout = (const float*)d_in[8];
  const float* bout = (const float*)d_in[9];
  const float* h0   = (const float*)d_in[10];
  const float* c0   = (const float*)d_in[11];

  net_persistent<<<dim3(NBLK), dim3(512), 0, stream>>>(
      Wih0, Whh0, b0, Wih1, Whh1, b1, gam, bet, Wout, bout, h0, c0,
      (float*)d_out, (uint32_t*)d_ws);
}